// Round 1
// baseline (52.604 us; speedup 1.0000x reference)
//
#include <hip/hip_runtime.h>

#define TPB 256

// ---------------- k1: per-row softmax stats + per-block count ----------------
__global__ void k1_rowstats(const float* __restrict__ outp,
                            float* __restrict__ pflag,
                            unsigned int* __restrict__ counts, int B) {
    int row = blockIdx.x * TPB + threadIdx.x;
    bool mask = false;
    if (row < B) {
        const float4* o4 = (const float4*)outp + (size_t)row * 4;
        float4 a = o4[0];
        float4 b = o4[1];
        float4 c = o4[2];
        float4 d = o4[3];
        float m01 = fmaxf(fmaxf(a.x, a.y), fmaxf(a.z, a.w));
        float m23 = fmaxf(fmaxf(b.x, b.y), fmaxf(b.z, b.w));
        float m45 = fmaxf(fmaxf(c.x, c.y), fmaxf(c.z, c.w));
        float m67 = fmaxf(fmaxf(d.x, d.y), fmaxf(d.z, d.w));
        float m = fmaxf(fmaxf(m01, m23), fmaxf(m45, m67));
        float s = __expf(a.x - m) + __expf(a.y - m) + __expf(a.z - m) + __expf(a.w - m)
                + __expf(b.x - m) + __expf(b.y - m) + __expf(b.z - m) + __expf(b.w - m)
                + __expf(c.x - m) + __expf(c.y - m) + __expf(c.z - m) + __expf(c.w - m)
                + __expf(d.x - m) + __expf(d.y - m) + __expf(d.z - m) + __expf(d.w - m);
        float p = 1.0f / s;            // max softmax prob
        mask = (a.x == m);             // first-occurrence argmax == 0
        pflag[row] = mask ? p : -1.0f;
    }
    unsigned long long bal = __ballot(mask);
    __shared__ unsigned int wtot[TPB / 64];
    int lane = threadIdx.x & 63;
    int wid  = threadIdx.x >> 6;
    if (lane == 0) wtot[wid] = (unsigned int)__popcll(bal);
    __syncthreads();
    if (threadIdx.x == 0)
        counts[blockIdx.x] = wtot[0] + wtot[1] + wtot[2] + wtot[3];
}

// ---------------- k2: single-block exclusive scan of block counts ------------
__global__ void k2_scan(unsigned int* __restrict__ counts, int nb,
                        unsigned int* __restrict__ total, float* __restrict__ out0) {
    __shared__ unsigned int sm[1024];
    unsigned int base = 0;
    for (int start = 0; start < nb; start += 1024) {
        int i = start + (int)threadIdx.x;
        unsigned int v = (i < nb) ? counts[i] : 0u;
        sm[threadIdx.x] = v;
        __syncthreads();
        for (int off = 1; off < 1024; off <<= 1) {
            unsigned int t = (threadIdx.x >= (unsigned)off) ? sm[threadIdx.x - off] : 0u;
            __syncthreads();
            sm[threadIdx.x] += t;
            __syncthreads();
        }
        if (i < nb) counts[i] = base + sm[threadIdx.x] - v;   // exclusive
        unsigned int chunk_total = sm[1023];
        __syncthreads();
        base += chunk_total;
    }
    if (threadIdx.x == 0) { *total = base; *out0 = 0.0f; }
}

// ---------------- k3: stable stream compaction of (p, score) -----------------
__global__ void k3_scatter(const float* __restrict__ pflag,
                           const float* __restrict__ score,
                           const unsigned int* __restrict__ offsets,
                           float* __restrict__ cp, float* __restrict__ cs, int B) {
    int row = blockIdx.x * TPB + threadIdx.x;
    float p = -1.0f;
    if (row < B) p = pflag[row];
    bool mask = (p >= 0.0f);
    unsigned long long bal = __ballot(mask);
    int lane = threadIdx.x & 63;
    int wid  = threadIdx.x >> 6;
    unsigned int wpre = (unsigned int)__popcll(bal & ((1ull << lane) - 1ull));
    __shared__ unsigned int wtot[TPB / 64];
    if (lane == 0) wtot[wid] = (unsigned int)__popcll(bal);
    __syncthreads();
    unsigned int base = offsets[blockIdx.x];
    for (int w = 0; w < wid; ++w) base += wtot[w];
    if (mask) {
        unsigned int pos = base + wpre;
        cp[pos] = p;
        cs[pos] = score[row];
    }
}

// ---------------- k4: adjacent-pair ranking loss over compact prefix ---------
__global__ void k4_pairs(const float* __restrict__ cp, const float* __restrict__ cs,
                         const unsigned int* __restrict__ total,
                         float* __restrict__ out) {
    int n = (int)*total;
    int limit = n - 1;
    float acc = 0.0f;
    int stride = gridDim.x * blockDim.x;
    for (int i = blockIdx.x * blockDim.x + threadIdx.x; i < limit; i += stride) {
        float dp = cp[i] - cp[i + 1];
        float ds = cs[i] - cs[i + 1];
        float sg = (ds > 0.0f) ? 1.0f : ((ds < 0.0f) ? -1.0f : 0.0f);
        float t  = dp * sg;
        // stable softplus(-t) = max(-t,0) + log1p(exp(-|t|))
        acc += fmaxf(-t, 0.0f) + log1pf(__expf(-fabsf(t)));
    }
    // wave reduce (64 lanes)
    for (int off = 32; off > 0; off >>= 1) acc += __shfl_down(acc, off);
    __shared__ float wsum[TPB / 64];
    int lane = threadIdx.x & 63;
    int wid  = threadIdx.x >> 6;
    if (lane == 0) wsum[wid] = acc;
    __syncthreads();
    if (threadIdx.x == 0) {
        float bs = wsum[0] + wsum[1] + wsum[2] + wsum[3];
        atomicAdd(out, bs);
    }
}

extern "C" void kernel_launch(void* const* d_in, const int* in_sizes, int n_in,
                              void* d_out, int out_size, void* d_ws, size_t ws_size,
                              hipStream_t stream) {
    const float* outp  = (const float*)d_in[0];   // [B,16] logits
    const float* score = (const float*)d_in[1];   // [B]
    float* out = (float*)d_out;

    int B  = in_sizes[1];
    int nb = (B + TPB - 1) / TPB;

    char* ws = (char*)d_ws;
    size_t szB = (size_t)B * sizeof(float);
    float*        pflag  = (float*)ws;
    float*        cp     = (float*)(ws + szB);
    float*        cs     = (float*)(ws + 2 * szB);
    unsigned int* counts = (unsigned int*)(ws + 3 * szB);
    unsigned int* total  = counts + nb;

    k1_rowstats<<<nb, TPB, 0, stream>>>(outp, pflag, counts, B);
    k2_scan<<<1, 1024, 0, stream>>>(counts, nb, total, out);
    k3_scatter<<<nb, TPB, 0, stream>>>(pflag, score, counts, cp, cs, B);
    k4_pairs<<<256, TPB, 0, stream>>>(cp, cs, total, out);
}

// Round 2
// 41.284 us; speedup vs baseline: 1.2742x; 1.2742x over previous
//
#include <hip/hip_runtime.h>

#define TPB 256
#define NW  (TPB / 64)

__device__ __forceinline__ float pair_loss(float p0, float s0, float p1, float s1) {
    float dp = p0 - p1;
    float ds = s0 - s1;
    float sg = (ds > 0.0f) ? 1.0f : ((ds < 0.0f) ? -1.0f : 0.0f);
    float t  = dp * sg;
    // stable softplus(-t) = max(-t,0) + log1p(exp(-|t|))
    return fmaxf(-t, 0.0f) + log1pf(__expf(-fabsf(t)));
}

// k1: per-row softmax top prob + mask; block-local adjacent-selected pair loss;
//     per-block boundary info for cross-block pairs.
__global__ void k1_rows(const float* __restrict__ outp,
                        const float* __restrict__ score,
                        float*  __restrict__ bpart,   // [nb] block-local loss sum
                        float2* __restrict__ bfirst,  // [nb] first selected (p,s)
                        float2* __restrict__ blast,   // [nb] last  selected (p,s)
                        unsigned int* __restrict__ bne, // [nb] block has selected?
                        int B) {
    __shared__ float sp[TPB];
    __shared__ float ss[TPB];
    __shared__ unsigned long long wmask[NW];
    __shared__ float wsum[NW];

    int row  = blockIdx.x * TPB + threadIdx.x;
    int lane = threadIdx.x & 63;
    int wid  = threadIdx.x >> 6;

    bool mask = false;
    float p = 0.0f, s = 0.0f;
    if (row < B) {
        const float4* o4 = (const float4*)outp + (size_t)row * 4;
        float4 a = o4[0];
        float4 b = o4[1];
        float4 c = o4[2];
        float4 d = o4[3];
        float m01 = fmaxf(fmaxf(a.x, a.y), fmaxf(a.z, a.w));
        float m23 = fmaxf(fmaxf(b.x, b.y), fmaxf(b.z, b.w));
        float m45 = fmaxf(fmaxf(c.x, c.y), fmaxf(c.z, c.w));
        float m67 = fmaxf(fmaxf(d.x, d.y), fmaxf(d.z, d.w));
        float m = fmaxf(fmaxf(m01, m23), fmaxf(m45, m67));
        float sum = __expf(a.x - m) + __expf(a.y - m) + __expf(a.z - m) + __expf(a.w - m)
                  + __expf(b.x - m) + __expf(b.y - m) + __expf(b.z - m) + __expf(b.w - m)
                  + __expf(c.x - m) + __expf(c.y - m) + __expf(c.z - m) + __expf(c.w - m)
                  + __expf(d.x - m) + __expf(d.y - m) + __expf(d.z - m) + __expf(d.w - m);
        p = 1.0f / sum;        // top softmax probability
        mask = (a.x == m);     // argmax (first occurrence) == 0
        s = score[row];        // coalesced full read
    }
    sp[threadIdx.x] = p;
    ss[threadIdx.x] = s;

    unsigned long long bal = __ballot(mask);
    if (lane == 0) wmask[wid] = bal;
    __syncthreads();

    float acc = 0.0f;
    if (mask) {
        // next selected thread index within this block
        unsigned long long above = bal & ~((2ull << lane) - 1ull); // lane 63 -> 0 (2<<63 == 0)
        int nxt = -1;
        if (above) {
            nxt = (wid << 6) + __ffsll(above) - 1;
        } else {
            for (int w = wid + 1; w < NW; ++w) {
                if (wmask[w]) { nxt = (w << 6) + __ffsll(wmask[w]) - 1; break; }
            }
        }
        if (nxt >= 0) {
            acc = pair_loss(p, s, sp[nxt], ss[nxt]);
        } else {
            blast[blockIdx.x] = make_float2(p, s);   // last selected in block
        }
        // first selected in block?
        bool first = ((bal & ((1ull << lane) - 1ull)) == 0ull);
        for (int w = 0; w < wid; ++w) if (wmask[w]) first = false;
        if (first) bfirst[blockIdx.x] = make_float2(p, s);
    }

    // block reduce acc
    for (int off = 32; off > 0; off >>= 1) acc += __shfl_down(acc, off);
    if (lane == 0) wsum[wid] = acc;
    __syncthreads();
    if (threadIdx.x == 0) {
        bpart[blockIdx.x] = wsum[0] + wsum[1] + wsum[2] + wsum[3];
        unsigned int any = 0;
        for (int w = 0; w < NW; ++w) any |= (wmask[w] != 0ull);
        bne[blockIdx.x] = any;
    }
}

// k2: single block — sum block partials + cross-block boundary pairs, write out.
__global__ void k2_final(const float*  __restrict__ bpart,
                         const float2* __restrict__ bfirst,
                         const float2* __restrict__ blast,
                         const unsigned int* __restrict__ bne,
                         int nb, float* __restrict__ out) {
    __shared__ float wsum[16];
    float acc = 0.0f;
    for (int b = threadIdx.x; b < nb; b += 1024) {
        acc += bpart[b];
        if (bne[b]) {
            for (int j = b + 1; j < nb; ++j) {
                if (bne[j]) {
                    float2 l = blast[b];
                    float2 f = bfirst[j];
                    acc += pair_loss(l.x, l.y, f.x, f.y);
                    break;
                }
            }
        }
    }
    int lane = threadIdx.x & 63;
    int wid  = threadIdx.x >> 6;
    for (int off = 32; off > 0; off >>= 1) acc += __shfl_down(acc, off);
    if (lane == 0) wsum[wid] = acc;
    __syncthreads();
    if (threadIdx.x == 0) {
        float t = 0.0f;
        for (int w = 0; w < 16; ++w) t += wsum[w];
        out[0] = t;
    }
}

extern "C" void kernel_launch(void* const* d_in, const int* in_sizes, int n_in,
                              void* d_out, int out_size, void* d_ws, size_t ws_size,
                              hipStream_t stream) {
    const float* outp  = (const float*)d_in[0];   // [B,16] logits
    const float* score = (const float*)d_in[1];   // [B]
    float* out = (float*)d_out;

    int B  = in_sizes[1];
    int nb = (B + TPB - 1) / TPB;

    char* ws = (char*)d_ws;
    float*        bpart  = (float*)ws;
    float2*       bfirst = (float2*)(ws + (size_t)nb * 4);
    float2*       blast  = (float2*)(ws + (size_t)nb * 12);
    unsigned int* bne    = (unsigned int*)(ws + (size_t)nb * 20);

    k1_rows<<<nb, TPB, 0, stream>>>(outp, score, bpart, bfirst, blast, bne, B);
    k2_final<<<1, 1024, 0, stream>>>(bpart, bfirst, blast, bne, nb, out);
}